// Round 7
// baseline (666.655 us; speedup 1.0000x reference)
//
#include <hip/hip_runtime.h>
#include <hip/hip_bf16.h>

constexpr int BB = 4096;   // batch
constexpr int TT = 2048;   // time
constexpr int HH = 32;     // hidden
constexpr int WPB = 4;     // waves per block (independent batch elems, NO barriers)

typedef float v2f __attribute__((ext_vector_type(2)));
typedef float v4f __attribute__((ext_vector_type(4)));
typedef _Float16 v2h __attribute__((ext_vector_type(2)));
typedef _Float16 v8h __attribute__((ext_vector_type(8)));

// ---------- fast math (v_exp_f32 / v_rcp_f32) ----------
__device__ __forceinline__ float fexp2(float x) { return __builtin_amdgcn_exp2f(x); }
__device__ __forceinline__ float frcp(float x)  { return __builtin_amdgcn_rcpf(x); }
__device__ __forceinline__ float fsigmoid(float x) {
    return frcp(1.0f + fexp2(x * -1.4426950408889634f));
}
__device__ __forceinline__ float felu(float x) {
    return x > 0.0f ? x : (fexp2(x * 1.4426950408889634f) - 1.0f);
}

// ---------- kernel 1: counting sort of batch indices by length, descending ----------
__global__ void sort_by_len_kernel(const int* __restrict__ lengths, int* __restrict__ perm) {
    __shared__ int hist[TT];     // key = TT - len  in [0, TT-1]
    __shared__ int csum[256];
    const int tid = threadIdx.x;
    for (int i = tid; i < TT; i += 256) hist[i] = 0;
    __syncthreads();
    for (int i = tid; i < BB; i += 256) atomicAdd(&hist[TT - lengths[i]], 1);
    __syncthreads();
    const int base = tid * 8;
    int loc[8];
    int s = 0;
#pragma unroll
    for (int j = 0; j < 8; ++j) { loc[j] = hist[base + j]; s += loc[j]; }
    csum[tid] = s;
    __syncthreads();
    for (int off = 1; off < 256; off <<= 1) {
        int v = (tid >= off) ? csum[tid - off] : 0;
        __syncthreads();
        csum[tid] += v;
        __syncthreads();
    }
    int run = csum[tid] - s;
#pragma unroll
    for (int j = 0; j < 8; ++j) { int t = loc[j]; hist[base + j] = run; run += t; }
    __syncthreads();
    for (int i = tid; i < BB; i += 256) {
        int pos = atomicAdd(&hist[TT - lengths[i]], 1);
        perm[pos] = i;
    }
}

// ---------- kernel 2: backward LSTM + MLP head ----------
// 256-thread blocks = 4 INDEPENDENT waves, each one batch element, no barriers.
// R5 post-mortem correction: the loop is LATENCY-bound (serial chain ~364 cyc:
// ds_read h -> fdot2 chain -> trans -> shfl -> ds_write), per-wave VALU issue is
// only ~100 cyc/step. Fix = occupancy (interleave more chains/SIMD), not ILP.
// R6 bug: reading hs through v4f* (float TBAA) let the compiler reorder the
// ds_read before the ds_write of the same step -> stale h. Fixed: v8h-typed
// reads (same TBAA class as the _Float16 store) + an explicit memory-order asm.
// Per-wave layout (unit n = lane&31):
//   lower lane n : rows i_n (r0) and g_n (r1)  -> ig = sig(i)*tanh(g)
//   upper lane n : rows f_n (r0) and o_n (r1)  -> owns c, h
// One __shfl_xor(ig,32)/step. f16 weights in 32 v2h regs, consumed by
// v_dot2_f32_f16. Rows pre-scaled by -log2e / -2log2e.
__global__ __attribute__((amdgpu_flat_work_group_size(256, 256), amdgpu_waves_per_eu(4, 8)))
void lstm_kernel(const float* __restrict__ x, const int* __restrict__ lengths,
                 const float* __restrict__ w_ih, const float* __restrict__ w_hh,
                 const float* __restrict__ b_ih, const float* __restrict__ b_hh,
                 const float* __restrict__ fc_w, const float* __restrict__ fc_b,
                 const float* __restrict__ fc2_w, const float* __restrict__ fc2_b,
                 float* __restrict__ out, const int* __restrict__ perm) {
    __shared__ __align__(16) _Float16 hs[WPB][64];  // [.][32..63] = h (upper lanes)
    __shared__ float xbuf[WPB][64];

    const int tid  = threadIdx.x;
    const int w    = tid >> 6;          // wave id in block
    const int lane = tid & 63;          // lane in wave
    const int bi   = blockIdx.x * WPB + w;
    const int b    = perm ? perm[bi] : bi;
    const int L    = lengths[b];

    const int r0 = lane;        // i (lower) / f (upper)
    const int r1 = lane + 64;   // g (lower) / o (upper)

    const bool  lower  = lane < 32;
    const float NL2E   = -1.4426950408889634f;
    const float scale0 = NL2E;                           // i/f: sigmoid
    const float scale1 = lower ? 2.0f * NL2E : NL2E;     // g: tanh, o: sigmoid
    const float amul   = lower ? 2.0f : 1.0f;
    const float badd   = lower ? -1.0f : 0.0f;

    // per-lane pre-scaled f16 weights in registers (32 VGPRs)
    v2h w0[16], w1[16];
    {
        const v2f* p0 = reinterpret_cast<const v2f*>(w_hh + r0 * 32);
        const v2f* p1 = reinterpret_cast<const v2f*>(w_hh + r1 * 32);
#pragma unroll
        for (int q = 0; q < 16; ++q) {
            v2f a = p0[q]; v2f bq = p1[q];
            w0[q] = (v2h){(_Float16)(a.x * scale0), (_Float16)(a.y * scale0)};
            w1[q] = (v2h){(_Float16)(bq.x * scale1), (_Float16)(bq.y * scale1)};
        }
    }
    float wi0 = w_ih[r0] * scale0;
    float wi1 = w_ih[r1] * scale1;
    float bi0 = (b_ih[r0] + b_hh[r0]) * scale0;
    float bi1 = (b_ih[r1] + b_hh[r1]) * scale1;

    v8h hr[4];
#pragma unroll
    for (int q = 0; q < 4; ++q) hr[q] = (v8h)(_Float16)0.0f;
    float c = 0.0f;
    const float* xb = x + (size_t)b * TT;

    int t = L - 1;
    while (t >= 0) {
        const int tb = t & ~63;
        xbuf[w][lane] = xb[tb + lane];   // wave-local staging, no barrier
        for (; t >= tb; --t) {
            const float xt = xbuf[w][t - tb];
            float a0  = fmaf(wi0, xt, bi0);
            float a1  = fmaf(wi1, xt, bi1);
            float a0b = 0.0f, a1b = 0.0f;
#pragma unroll
            for (int q = 0; q < 4; ++q) {
                const v8h hh = hr[q];
                const v2h p01 = __builtin_shufflevector(hh, hh, 0, 1);
                const v2h p23 = __builtin_shufflevector(hh, hh, 2, 3);
                const v2h p45 = __builtin_shufflevector(hh, hh, 4, 5);
                const v2h p67 = __builtin_shufflevector(hh, hh, 6, 7);
                a0  = __builtin_amdgcn_fdot2(w0[4*q+0], p01, a0,  false);
                a0b = __builtin_amdgcn_fdot2(w0[4*q+1], p23, a0b, false);
                a0  = __builtin_amdgcn_fdot2(w0[4*q+2], p45, a0,  false);
                a0b = __builtin_amdgcn_fdot2(w0[4*q+3], p67, a0b, false);
                a1  = __builtin_amdgcn_fdot2(w1[4*q+0], p01, a1,  false);
                a1b = __builtin_amdgcn_fdot2(w1[4*q+1], p23, a1b, false);
                a1  = __builtin_amdgcn_fdot2(w1[4*q+2], p45, a1,  false);
                a1b = __builtin_amdgcn_fdot2(w1[4*q+3], p67, a1b, false);
            }
            const float g0 = a0 + a0b;     // pre-scaled gate inputs
            const float g1 = a1 + a1b;
            const float s0 = frcp(1.0f + fexp2(g0));   // sig(i) / sig(f)
            const float s1 = frcp(1.0f + fexp2(g1));
            const float v1 = fmaf(amul, s1, badd);     // tanh(g) / sig(o)
            const float ig = s0 * v1;                  // lower: i*g
            const float igx = __shfl_xor(ig, 32);
            c = fmaf(s0, c, igx);                      // upper lanes: c = f*c + i*g
            const float tc = 1.0f - 2.0f * frcp(1.0f + fexp2(c * 2.8853900817779268f));
            const float hn = v1 * tc;                  // upper: sig(o)*tanh(c)
            hs[w][lane] = (_Float16)hn;                // h lands at hs[w][32..63]
            asm volatile("" ::: "memory");             // order: write before re-read
            const v8h* hp = reinterpret_cast<const v8h*>(&hs[w][32]);
#pragma unroll
            for (int q = 0; q < 4; ++q) hr[q] = hp[q]; // 16B broadcast reads (same TBAA)
        }
    }

    // ---- head: out[b] = sigmoid( sum_r fc2_w[r]*elu(fc_w[r]@h + fc_b[r]) + fc2_b ) ----
    float hf[32];
#pragma unroll
    for (int q = 0; q < 4; ++q) {
        const v8h hh = hr[q];
#pragma unroll
        for (int j = 0; j < 8; ++j) hf[8 * q + j] = (float)hh[j];
    }
    float a = fc_b[lane];
    {
        const v4f* fp = reinterpret_cast<const v4f*>(fc_w + lane * 32);
#pragma unroll
        for (int q = 0; q < 8; ++q) {
            const v4f f = fp[q];
            a = fmaf(f.x, hf[4 * q + 0], a);
            a = fmaf(f.y, hf[4 * q + 1], a);
            a = fmaf(f.z, hf[4 * q + 2], a);
            a = fmaf(f.w, hf[4 * q + 3], a);
        }
    }
    float partial = felu(a) * fc2_w[lane];
#pragma unroll
    for (int m = 32; m >= 1; m >>= 1) partial += __shfl_xor(partial, m, 64);
    if (lane == 0) out[b] = fsigmoid(partial + fc2_b[0]);
}

extern "C" void kernel_launch(void* const* d_in, const int* in_sizes, int n_in,
                              void* d_out, int out_size, void* d_ws, size_t ws_size,
                              hipStream_t stream) {
    const float* x       = (const float*)d_in[0];
    const int*   lengths = (const int*)d_in[1];
    const float* w_ih    = (const float*)d_in[2];
    const float* w_hh    = (const float*)d_in[3];
    const float* b_ih    = (const float*)d_in[4];
    const float* b_hh    = (const float*)d_in[5];
    const float* fc_w    = (const float*)d_in[6];
    const float* fc_b    = (const float*)d_in[7];
    const float* fc2_w   = (const float*)d_in[8];
    const float* fc2_b   = (const float*)d_in[9];
    float* out = (float*)d_out;

    int* perm = nullptr;
    if (ws_size >= (size_t)BB * sizeof(int)) {
        perm = (int*)d_ws;
        hipLaunchKernelGGL(sort_by_len_kernel, dim3(1), dim3(256), 0, stream, lengths, perm);
    }
    hipLaunchKernelGGL(lstm_kernel, dim3(BB / WPB), dim3(64 * WPB), 0, stream,
                       x, lengths, w_ih, w_hh, b_ih, b_hh,
                       fc_w, fc_b, fc2_w, fc2_b, out, perm);
}